// Round 14
// baseline (72.262 us; speedup 1.0000x reference)
//
#include <hip/hip_runtime.h>
#include <hip/hip_bf16.h>

#define NP 512                     // particles
#define DD 128                     // dims
#define NPAIRS (NP * (NP - 1) / 2) // 130816

// Hybrid bitonic sort of 512 floats (ascending): value in register r, one per
// thread; __shfl_xor for partner distance < 64, LDS exchange for s >= 64.
__device__ __forceinline__ float bitonic512(float r, int tid, float* lds)
{
    for (int k = 2; k <= NP; k <<= 1) {
        for (int s = k >> 1; s > 0; s >>= 1) {
            float other;
            if (s < 64) {
                other = __shfl_xor(r, s);
            } else {
                __syncthreads();
                lds[tid] = r;
                __syncthreads();
                other = lds[tid ^ s];
            }
            const bool lower = (tid & s) == 0;
            const bool up    = (tid & k) == 0;
            r = (lower == up) ? fminf(r, other) : fmaxf(r, other);
        }
    }
    return r;
}

// ---------------------------------------------------------------------------
// Kernel 1: per-dimension exact median of upper-triangular pairwise squared
// differences. One block (512 threads) per dimension d.
//   1) bitonic sort -> v[] (LDS); thread owns j = tid, vj = v[j]
//   2) verified-pivot rounds: seeds at 0.93x/1.07x band-150 mean (R13,
//      proven), then TARGETED INTERPOLATION: aim the count at want1 +/- 240
//      (tighten whichever bracket side is slacker; density inside the seeded
//      bracket is near-uniform so interp lands within ~100 of target);
//      bit-midpoint safeguard every 4th round. Every pivot VERIFIED by exact
//      count — correctness never depends on the policy. count via per-j warm
//      windows [A,B] + select-only binary search. 1 barrier/round.
//   3) endgame when T <= 512: gather candidates (prefix-sum offsets), then
//      COUNTING-SELECT (no second sort): pad to 512 with +INF, each thread
//      counts {#<c, #==c} via 128 broadcast float4 LDS reads; the rank-rr
//      value satisfies cl < rr <= cl+ce (duplicate writers write same value).
//   median(squared diffs) = Dk*Dk (x -> fl(x^2) monotone on non-neg floats)
// ---------------------------------------------------------------------------
__global__ void __launch_bounds__(512)
median_bw_kernel(const float* __restrict__ particles, float* __restrict__ inv_bw)
{
    const int d = blockIdx.x, tid = threadIdx.x, lane = tid & 63, wid = tid >> 6;

    __shared__ float v[NP];
    __shared__ __align__(16) float cand[NP];
    __shared__ int   cnt_s[2][8];
    __shared__ float sum_s[8];
    __shared__ int   scan_s[8];

    float r = particles[tid * DD + d];
    r = bitonic512(r, tid, v);
    __syncthreads();          // WAR vs last cross-stage reads inside sort
    v[tid] = r;
    __syncthreads();          // sorted array visible to all

    const float vj = r;       // sorted value owned by this thread (j = tid)
    const int want1 = (NPAIRS - 1) / 2 + 1;   // 65408 (1-based rank)

    // ---- band-150 mean: the rank-65408 pair sits at sorted offset ~150 ----
    float s = (tid >= 150) ? (vj - v[tid - 150]) : 0.0f;
    #pragma unroll
    for (int off = 32; off > 0; off >>= 1) s += __shfl_xor(s, off);
    if (lane == 0) sum_s[wid] = s;
    __syncthreads();
    float msum = 0.0f;
    #pragma unroll
    for (int w = 0; w < 8; ++w) msum += sum_s[w];
    const float meanp = fmaxf(msum / 362.0f, 0.0f);   // uniform across block

    const float maxd = v[NP - 1] - v[0];
    unsigned lo = 0u;
    unsigned hi = __float_as_uint(maxd) + 1u;   // answer bits in [lo, hi]
    int C_lo = 0;                   // count at pred(lo)   (< want1)
    int C_hi = NPAIRS;              // count at hi         (>= want1)
    int A = 0, B = tid;             // warm window: A <= L_j(x) <= B, x in [lo,hi]
    int buf = 0, round = 0;

    while (lo < hi) {
        if (C_hi - C_lo <= NP) break;    // endgame

        unsigned mid;
        if (round == 0) {
            mid = __float_as_uint(0.93f * meanp);   // seed: low side
        } else if (round == 1) {
            mid = __float_as_uint(1.07f * meanp);   // seed: high side
        } else if ((round & 3) == 3) {              // safeguard: bit midpoint
            mid = lo + ((hi - lo) >> 1);
        } else {                                    // targeted interpolation
            const int upslack = C_hi - want1;
            const int dnslack = want1 - 1 - C_lo;
            int target = (upslack >= dnslack) ? (want1 + 240) : (want1 - 240);
            if (target <= C_lo) target = C_lo + 1;
            if (target >  C_hi) target = C_hi;
            const float frac = (float)(target - C_lo) / (float)(C_hi - C_lo);
            const float flo  = __uint_as_float(lo);
            const float fhi  = __uint_as_float(hi);
            mid = __float_as_uint(flo + (fhi - flo) * frac);
        }
        if (mid < lo)      mid = lo;
        if (mid > hi - 1u) mid = hi - 1u;
        const float x = __uint_as_float(mid);

        // warm-started select-only lower_bound in [A,B] (proven primitive)
        int a = A, b = B;
        while (a < b) {
            const int   m  = (a + b) >> 1;
            const float pv = v[m];
            const bool  t  = (vj - pv <= x);
            b = t ? m : b;
            a = t ? a : m + 1;
        }
        int cnt = tid - a;               // #{i<j : fl(vj-vi) <= x}

        #pragma unroll
        for (int off = 32; off > 0; off >>= 1) cnt += __shfl_xor(cnt, off);
        if (lane == 0) cnt_s[buf][wid] = cnt;
        __syncthreads();                 // the ONLY barrier in the round
        int tot = 0;
        #pragma unroll
        for (int w = 0; w < 8; ++w) tot += cnt_s[buf][w];

        if (tot >= want1) { hi = mid;      C_hi = tot; A = a; }
        else              { lo = mid + 1u; C_lo = tot; B = a; }
        buf ^= 1;
        ++round;
    }

    if (lo >= hi) {
        // bracket collapsed to a single bit pattern: that's the answer
        if (tid == 0) {
            const float Dk = __uint_as_float(lo);
            const float h  = (Dk * Dk) / 6.240275844172107f;  // ln(513)
            inv_bw[d] = 1.0f / fmaxf(h, 1e-9f);
        }
    } else {
        // ---- endgame: T (<=512) candidates, rank rr within them ----
        const int T  = C_hi - C_lo;
        const int rr = min(want1 - C_lo, T);  // 1-based, 1 <= rr <= T
        const int n  = B - A;                 // this thread's candidates
        cand[tid] = INFINITY;                 // pad for counting-select
        int inc = n;                          // wave inclusive scan
        #pragma unroll
        for (int off = 1; off < 64; off <<= 1) {
            const int t = __shfl_up(inc, off);
            if (lane >= off) inc += t;
        }
        if (lane == 63) scan_s[wid] = inc;
        __syncthreads();
        int woff = 0;
        #pragma unroll
        for (int w = 0; w < 8; ++w) woff += (w < wid) ? scan_s[w] : 0;
        int off0 = woff + inc - n;            // exclusive global offset
        for (int i = A; i < B; ++i) cand[off0++] = vj - v[i];
        __syncthreads();

        // counting-select: value with cl < rr <= cl+ce is the rank-rr value
        const float c = cand[tid];
        int cl = 0, ce = 0;
        const float4* c4 = (const float4*)cand;
        #pragma unroll 4
        for (int k4 = 0; k4 < NP / 4; ++k4) {
            const float4 q = c4[k4];          // broadcast read
            cl += (q.x <  c) + (q.y <  c) + (q.z <  c) + (q.w <  c);
            ce += (q.x == c) + (q.y == c) + (q.z == c) + (q.w == c);
        }
        if (tid < T && cl < rr && rr <= cl + ce) {
            const float Dk = c;
            const float h  = (Dk * Dk) / 6.240275844172107f;  // ln(513)
            inv_bw[d] = 1.0f / fmaxf(h, 1e-9f);
        }
    }
}

// ---------------------------------------------------------------------------
// Kernel 2: write log_kernel and grad_log_kernel as ONE flat float4 stream
// (first half lk, second half g): each block writes a single contiguous
// linear run, matching the 7.0-7.2 TB/s fill-kernel pattern (two interleaved
// streams measured ~6.5). The lk/g branch is wave-uniform (half boundary is
// a multiple of the grid span). PLAIN stores (nt regressed 2.4x in R4).
// ---------------------------------------------------------------------------
__global__ void __launch_bounds__(256)
stein_out_kernel(const float* __restrict__ particles,
                 const float* __restrict__ inv_bw,
                 float4* __restrict__ out)
{
    const float4* __restrict__ p4  = (const float4*)particles;
    const float4* __restrict__ ib4 = (const float4*)inv_bw;
    const int half = NP * NP * (DD / 4);    // 8,388,608 float4s per output

    for (int u = blockIdx.x * blockDim.x + threadIdx.x; u < 2 * half;
         u += gridDim.x * blockDim.x) {
        const bool isg = (u >= half);       // wave-uniform
        const int t  = isg ? u - half : u;
        const int d4 = t & (DD / 4 - 1);    // 0..31
        const int j  = (t >> 5) & (NP - 1); // 0..511
        const int i  = t >> 14;             // 0..511

        const float4 xj = p4[j * (DD / 4) + d4];
        const float4 xi = p4[i * (DD / 4) + d4];
        const float4 ib = ib4[d4];

        const float dx0 = xj.x - xi.x;
        const float dx1 = xj.y - xi.y;
        const float dx2 = xj.z - xi.z;
        const float dx3 = xj.w - xi.w;

        float4 o;
        if (!isg) {
            o.x = -(dx0 * dx0 * ib.x);
            o.y = -(dx1 * dx1 * ib.y);
            o.z = -(dx2 * dx2 * ib.z);
            o.w = -(dx3 * dx3 * ib.w);
        } else {
            o.x = -2.0f * dx0 * ib.x;
            o.y = -2.0f * dx1 * ib.y;
            o.z = -2.0f * dx2 * ib.z;
            o.w = -2.0f * dx3 * ib.w;
        }
        out[u] = o;
    }
}

extern "C" void kernel_launch(void* const* d_in, const int* in_sizes, int n_in,
                              void* d_out, int out_size, void* d_ws, size_t ws_size,
                              hipStream_t stream)
{
    const float* particles = (const float*)d_in[0];
    float* out    = (float*)d_out;
    float* inv_bw = (float*)d_ws;   // 128 floats of scratch

    median_bw_kernel<<<DD, 512, 0, stream>>>(particles, inv_bw);
    stein_out_kernel<<<2048, 256, 0, stream>>>(particles, inv_bw, (float4*)out);
}

// Round 15
// 64.079 us; speedup vs baseline: 1.1277x; 1.1277x over previous
//
#include <hip/hip_runtime.h>
#include <hip/hip_bf16.h>

#define NP 512                     // particles
#define DD 128                     // dims
#define NPAIRS (NP * (NP - 1) / 2) // 130816

// Hybrid bitonic sort of 512 floats (ascending): value in register r, one per
// thread; __shfl_xor for partner distance < 64, LDS exchange for s >= 64.
__device__ __forceinline__ float bitonic512(float r, int tid, float* lds)
{
    for (int k = 2; k <= NP; k <<= 1) {
        for (int s = k >> 1; s > 0; s >>= 1) {
            float other;
            if (s < 64) {
                other = __shfl_xor(r, s);
            } else {
                __syncthreads();
                lds[tid] = r;
                __syncthreads();
                other = lds[tid ^ s];
            }
            const bool lower = (tid & s) == 0;
            const bool up    = (tid & k) == 0;
            r = (lower == up) ? fminf(r, other) : fmaxf(r, other);
        }
    }
    return r;
}

// ---------------------------------------------------------------------------
// Kernel 1: per-dimension exact median of upper-triangular pairwise squared
// differences. One block (512 threads) per dimension d.  (R13, proven 64.4us)
//   1) bitonic sort -> v[] (LDS); thread owns j = tid, vj = v[j]
//   2) verified-pivot rounds, SEEDED RANK-BISECTION policy:
//      rounds 0/1 seed a tight bracket at 0.93x / 1.07x the band-150 mean
//      (band mean ~ the answer; a miss merely degrades to plain bisection
//      since every pivot is VERIFIED by an exact count). Rounds >= 2 use the
//      VALUE-space midpoint (flo+fhi)/2: inside the seeded bracket the diff
//      density is near-uniform, so T = C_hi - C_lo halves per round.
//      count via per-j warm windows [A,B] + select-only binary search
//      (proven primitive). 1 barrier per round.
//   3) endgame when T <= 512: gather candidates (prefix-sum offsets), one
//      bitonic sort, answer = rank (want1 - C_lo).
//   median(squared diffs) = Dk*Dk (x -> fl(x^2) monotone on non-neg floats)
// ---------------------------------------------------------------------------
__global__ void __launch_bounds__(512)
median_bw_kernel(const float* __restrict__ particles, float* __restrict__ inv_bw)
{
    const int d = blockIdx.x, tid = threadIdx.x, lane = tid & 63, wid = tid >> 6;

    __shared__ float v[NP];
    __shared__ float cand[NP];
    __shared__ int   cnt_s[2][8];
    __shared__ float sum_s[8];
    __shared__ int   scan_s[8];

    float r = particles[tid * DD + d];
    r = bitonic512(r, tid, v);
    __syncthreads();          // WAR vs last cross-stage reads inside sort
    v[tid] = r;
    __syncthreads();          // sorted array visible to all

    const float vj = r;       // sorted value owned by this thread (j = tid)
    const int want1 = (NPAIRS - 1) / 2 + 1;   // 65408 (1-based rank)

    // ---- band-150 mean: the rank-65408 pair sits at sorted offset ~150 ----
    float s = (tid >= 150) ? (vj - v[tid - 150]) : 0.0f;
    #pragma unroll
    for (int off = 32; off > 0; off >>= 1) s += __shfl_xor(s, off);
    if (lane == 0) sum_s[wid] = s;
    __syncthreads();
    float msum = 0.0f;
    #pragma unroll
    for (int w = 0; w < 8; ++w) msum += sum_s[w];
    const float meanp = fmaxf(msum / 362.0f, 0.0f);   // uniform across block

    const float maxd = v[NP - 1] - v[0];
    unsigned lo = 0u;
    unsigned hi = __float_as_uint(maxd) + 1u;   // answer bits in [lo, hi]
    int C_lo = 0;                   // count at pred(lo)   (< want1)
    int C_hi = NPAIRS;              // count at hi         (>= want1)
    int A = 0, B = tid;             // warm window: A <= L_j(x) <= B, x in [lo,hi]
    int buf = 0, round = 0;

    while (lo < hi) {
        if (C_hi - C_lo <= NP) break;    // endgame

        unsigned mid;
        if (round == 0) {
            mid = __float_as_uint(0.93f * meanp);   // seed: low side
        } else if (round == 1) {
            mid = __float_as_uint(1.07f * meanp);   // seed: high side
        } else {                                    // value-space midpoint
            const float flo = __uint_as_float(lo);
            const float fhi = __uint_as_float(hi);
            mid = __float_as_uint(0.5f * (flo + fhi));
        }
        if (mid < lo)      mid = lo;
        if (mid > hi - 1u) mid = hi - 1u;
        const float x = __uint_as_float(mid);

        // warm-started select-only lower_bound in [A,B] (proven primitive)
        int a = A, b = B;
        while (a < b) {
            const int   m  = (a + b) >> 1;
            const float pv = v[m];
            const bool  t  = (vj - pv <= x);
            b = t ? m : b;
            a = t ? a : m + 1;
        }
        int cnt = tid - a;               // #{i<j : fl(vj-vi) <= x}

        #pragma unroll
        for (int off = 32; off > 0; off >>= 1) cnt += __shfl_xor(cnt, off);
        if (lane == 0) cnt_s[buf][wid] = cnt;
        __syncthreads();                 // the ONLY barrier in the round
        int tot = 0;
        #pragma unroll
        for (int w = 0; w < 8; ++w) tot += cnt_s[buf][w];

        if (tot >= want1) { hi = mid;      C_hi = tot; A = a; }
        else              { lo = mid + 1u; C_lo = tot; B = a; }
        buf ^= 1;
        ++round;
    }

    if (lo >= hi) {
        // bracket collapsed to a single bit pattern: that's the answer
        if (tid == 0) {
            const float Dk = __uint_as_float(lo);
            const float h  = (Dk * Dk) / 6.240275844172107f;  // ln(513)
            inv_bw[d] = 1.0f / fmaxf(h, 1e-9f);
        }
    } else {
        // ---- endgame: T (<=512) candidates, rank rr within them ----
        const int T  = C_hi - C_lo;
        const int rr = min(want1 - C_lo, T);  // 1-based, 1 <= rr <= T
        const int n  = B - A;                 // this thread's candidates
        int inc = n;                          // wave inclusive scan
        #pragma unroll
        for (int off = 1; off < 64; off <<= 1) {
            const int t = __shfl_up(inc, off);
            if (lane >= off) inc += t;
        }
        if (lane == 63) scan_s[wid] = inc;
        __syncthreads();
        int woff = 0;
        #pragma unroll
        for (int w = 0; w < 8; ++w) woff += (w < wid) ? scan_s[w] : 0;
        int off0 = woff + inc - n;            // exclusive global offset
        for (int i = A; i < B; ++i) cand[off0++] = vj - v[i];
        __syncthreads();

        float c = (tid < T) ? cand[tid] : INFINITY;
        c = bitonic512(c, tid, v);            // v reusable as scratch now

        if (tid == rr - 1) {
            const float Dk = c;
            const float h  = (Dk * Dk) / 6.240275844172107f;  // ln(513)
            inv_bw[d] = 1.0f / fmaxf(h, 1e-9f);
        }
    }
}

// ---------------------------------------------------------------------------
// Kernel 2: write log_kernel and grad_log_kernel, float4-vectorized,
// PLAIN stores (nontemporal stores regressed write BW ~2.4x in R4; flat
// single-stream variant regressed in R14 — two contiguous runs per wave is
// already write-combine-friendly).
// Flat float4 index t over (i, j, d4):  d4 = t & 31, j = (t>>5)&511, i = t>>14
// ---------------------------------------------------------------------------
__global__ void __launch_bounds__(256)
stein_out_kernel(const float* __restrict__ particles,
                 const float* __restrict__ inv_bw,
                 float4* __restrict__ out_lk,
                 float4* __restrict__ out_g)
{
    const float4* __restrict__ p4  = (const float4*)particles;
    const float4* __restrict__ ib4 = (const float4*)inv_bw;
    const int total = NP * NP * (DD / 4);   // 8,388,608

    for (int t = blockIdx.x * blockDim.x + threadIdx.x; t < total;
         t += gridDim.x * blockDim.x) {
        const int d4 = t & (DD / 4 - 1);        // 0..31
        const int j  = (t >> 5) & (NP - 1);     // 0..511
        const int i  = t >> 14;                 // 0..511

        const float4 xj = p4[j * (DD / 4) + d4];
        const float4 xi = p4[i * (DD / 4) + d4];
        const float4 ib = ib4[d4];

        float4 lk, g;
        {
            const float dx = xj.x - xi.x;
            lk.x = -(dx * dx * ib.x);
            g.x  = -2.0f * dx * ib.x;
        }
        {
            const float dx = xj.y - xi.y;
            lk.y = -(dx * dx * ib.y);
            g.y  = -2.0f * dx * ib.y;
        }
        {
            const float dx = xj.z - xi.z;
            lk.z = -(dx * dx * ib.z);
            g.z  = -2.0f * dx * ib.z;
        }
        {
            const float dx = xj.w - xi.w;
            lk.w = -(dx * dx * ib.w);
            g.w  = -2.0f * dx * ib.w;
        }
        out_lk[t] = lk;
        out_g[t]  = g;
    }
}

extern "C" void kernel_launch(void* const* d_in, const int* in_sizes, int n_in,
                              void* d_out, int out_size, void* d_ws, size_t ws_size,
                              hipStream_t stream)
{
    const float* particles = (const float*)d_in[0];
    float* out    = (float*)d_out;
    float* inv_bw = (float*)d_ws;   // 128 floats of scratch

    median_bw_kernel<<<DD, 512, 0, stream>>>(particles, inv_bw);

    float4* out_lk = (float4*)out;
    float4* out_g  = (float4*)(out + (size_t)NP * NP * DD);
    stein_out_kernel<<<2048, 256, 0, stream>>>(particles, inv_bw, out_lk, out_g);
}